// Round 11
// baseline (58.692 us; speedup 1.0000x reference)
//
#include <hip/hip_runtime.h>
#include <hip/hip_bf16.h>
#include <stdint.h>

// NT-Xent loss, B=4096, D=256, T=0.5, eps=1e-8.
// loss_r = log(sum_{c!=r} exp(2*dot(zn_r,zn_c))) - 2*dot(zin_r, zjn_r); out = mean.
// zn_s = zn * sqrt(2*log2e) stored bf16 -> MFMA acc = 2*log2e*dot -> exp2(acc) direct.
// Diagonal accumulated unconditionally; subtracted in k_loss via exp2(diag).
//
// R11: SYMMETRY. exp(sim) is symmetric -> compute only upper-triangle tiles.
// Grid = 32 diag tiles (full 256x256, row-partials only) + 496 strict-upper tiles
// (row-partials to slot[b] AND col-partials to slot[a]). Every slot[k][r] has
// exactly one writer -> deterministic, no atomics. Work = 51.6% of R10.
//
// LESSONS (R2..R10): launch_bounds arg2>2 / 512-thr / grid>512 all spill or
// thrash; 2 waves/SIMD with pinned afrag + dbuf-stage-early (R3 structure) is
// the proven-clean regime. VGPR=128, WRITE~2MB, conflicts 0 are the health checks.

#define BROWS 4096
#define DIM   256
#define N2    8192

typedef __attribute__((ext_vector_type(4))) float          f32x4;
typedef __attribute__((ext_vector_type(8))) short          s16x8;
typedef __attribute__((ext_vector_type(4))) unsigned short u16x4;

#define S_EXP  1.6986436597467051f   /* sqrt(2*log2(e)) */
#define LN2    0.6931471805599453f

__device__ inline unsigned short f2bf(float f) {
    uint32_t b = __float_as_uint(f);
    b += 0x7fffu + ((b >> 16) & 1u);   // RNE
    return (unsigned short)(b >> 16);
}
__device__ inline float bf2f(unsigned short u) {
    return __uint_as_float(((uint32_t)u) << 16);
}

__device__ inline void gload_lds16(const void* g, void* l) {
    __builtin_amdgcn_global_load_lds(
        (const __attribute__((address_space(1))) uint32_t*)g,
        (__attribute__((address_space(3))) uint32_t*)l, 16, 0, 0);
}

__device__ inline float wave_reduce(float v) {
    #pragma unroll
    for (int m = 1; m < 64; m <<= 1) v += __shfl_xor(v, m);
    return v;
}

// ---- K1: fused normalize (both views) + positive-pair exponent + diag self-dot ----
__global__ __launch_bounds__(256) void k_norm_pos(const float* __restrict__ zi,
                                                  const float* __restrict__ zj,
                                                  unsigned short* __restrict__ zn,
                                                  float* __restrict__ diag,
                                                  float* __restrict__ posv,
                                                  unsigned int* __restrict__ counter) {
    if (blockIdx.x == 0 && threadIdx.x == 0) *counter = 0u;
    int i    = blockIdx.x * 4 + (threadIdx.x >> 6);
    int lane = threadIdx.x & 63;
    f32x4 a = *(const f32x4*)(zi + (size_t)i * DIM + lane * 4);
    f32x4 b = *(const f32x4*)(zj + (size_t)i * DIM + lane * 4);
    float ssa = a[0]*a[0] + a[1]*a[1] + a[2]*a[2] + a[3]*a[3];
    float ssb = b[0]*b[0] + b[1]*b[1] + b[2]*b[2] + b[3]*b[3];
    float dab = a[0]*b[0] + a[1]*b[1] + a[2]*b[2] + a[3]*b[3];
    ssa = wave_reduce(ssa);
    ssb = wave_reduce(ssb);
    dab = wave_reduce(dab);
    float na = 1.0f / fmaxf(sqrtf(ssa), 1e-8f);
    float nb = 1.0f / fmaxf(sqrtf(ssb), 1e-8f);
    if (lane == 0) posv[i] = 2.0f * dab * na * nb;   // natural-log exponent of pos pair

    float sa = na * S_EXP, sb = nb * S_EXP;
    u16x4 oa, ob;
    float da = 0.0f, db = 0.0f;
    #pragma unroll
    for (int k = 0; k < 4; ++k) {
        unsigned short ua = f2bf(a[k] * sa);
        unsigned short ub = f2bf(b[k] * sb);
        oa[k] = ua; ob[k] = ub;
        float fa = bf2f(ua), fb = bf2f(ub);
        da += fa * fa; db += fb * fb;
    }
    *(u16x4*)(zn + (size_t)i * DIM + lane * 4)           = oa;
    *(u16x4*)(zn + (size_t)(i + BROWS) * DIM + lane * 4) = ob;
    da = wave_reduce(da);
    db = wave_reduce(db);
    if (lane == 0) { diag[i] = da; diag[i + BROWS] = db; }
}

// ---- K2: upper-triangle fused sim GEMM + exp2 + row/col sums ----
// Grid 528: bid<32 -> diagonal tile (a,a); bid>=32 -> strict-upper (a<b).
// 256 thr = 4 waves; tile 256 rows x 256 cols, 4 steps of 64 cols.
// Wave owns 64 rows (afrag[4][8] pinned, 128 VGPR). B dbuf LDS 2x32KB,
// staged BEFORE compute. Row-partials: shfl over cl -> partial[b*N2+row].
// Col-partials (off-diag only): per (s,ct) a lane's 16 acc values share one
// column -> scalar add; reduce over g via 2 shfl; cross-wave via ldsC ping-pong.
__global__ __launch_bounds__(256, 2) void k_simsum(const unsigned short* __restrict__ zn,
                                                   float* __restrict__ partial) {
    __shared__ unsigned short lds[2][64 * DIM];   // 2 x 32 KB
    __shared__ float ldsC[2][4][64];              // 2 x 1 KB col-partial strips

    int bid = blockIdx.x;
    int a, b;
    if (bid < 32) {
        a = bid; b = bid;
    } else {
        int k = bid - 32;                       // strict-upper pair index, 0..495
        a = (int)((63.0f - sqrtf(3969.0f - 8.0f * (float)k)) * 0.5f);
        if (a < 0) a = 0; if (a > 30) a = 30;
        while ((a + 1) * (62 - a) / 2 <= k) ++a;   // S(a+1) <= k -> advance
        while (a * (63 - a) / 2 > k) --a;          // S(a)  > k -> back off
        b = k - a * (63 - a) / 2 + a + 1;
    }
    bool offdiag = (a != b);
    int rowbase = a * 256;
    int colbase = b * 256;
    int tid = threadIdx.x, lane = tid & 63, w = tid >> 6;   // w in 0..3
    int cl = lane & 15, g = lane >> 4;

    // A fragments: lane holds zn[rowbase + w*64 + rt*16 + cl][kc*32 + g*8 .. +8]
    s16x8 afrag[4][8];
    #pragma unroll
    for (int rt = 0; rt < 4; ++rt) {
        int row = rowbase + w * 64 + rt * 16 + cl;
        const unsigned short* ap = zn + (size_t)row * DIM + g * 8;
        #pragma unroll
        for (int kc = 0; kc < 8; ++kc)
            afrag[rt][kc] = *(const s16x8*)(ap + kc * 32);
    }

    float pp[4][4];
    #pragma unroll
    for (int rt = 0; rt < 4; ++rt)
        #pragma unroll
        for (int r = 0; r < 4; ++r) pp[rt][r] = 0.0f;

    // stage 64 cols x 256 K into lds[buf]; 256 lanes x 16 B x 8 issues = 32 KB
    auto stage = [&](int buf, int s) {
        int crow = colbase + s * 64 + lane;
        const unsigned short* gsrc = zn + (size_t)crow * DIM;
        char* base = (char*)&lds[buf][0];
        #pragma unroll
        for (int i = 0; i < 8; ++i)
            gload_lds16(gsrc + i * 32 + w * 8, base + i * 4096 + w * 1024);
    };

    stage(0, 0);
    __syncthreads();   // prologue: buf0 ready

    for (int s = 0; s < 4; ++s) {
        int cur = s & 1;
        if (s < 3) stage(cur ^ 1, s + 1);   // issue next-tile loads BEFORE compute

        const char* lbase = (const char*)&lds[cur][0];
        #pragma unroll
        for (int ct = 0; ct < 4; ++ct) {
            f32x4 acc[4];
            #pragma unroll
            for (int rt = 0; rt < 4; ++rt) acc[rt] = (f32x4){0.f, 0.f, 0.f, 0.f};
            #pragma unroll
            for (int kc = 0; kc < 8; ++kc) {
                s16x8 bfrag = *(const s16x8*)(lbase + kc * 4096 + g * 1024 +
                                              (ct * 16 + cl) * 16);
                #pragma unroll
                for (int rt = 0; rt < 4; ++rt)
                    acc[rt] = __builtin_amdgcn_mfma_f32_16x16x32_bf16(
                                  afrag[rt][kc], bfrag, acc[rt], 0, 0, 0);
            }
            float ce = 0.0f;   // this lane's col-partial for col ct*16+cl (rows: its g-quarter)
            #pragma unroll
            for (int rt = 0; rt < 4; ++rt)
                #pragma unroll
                for (int r = 0; r < 4; ++r) {
                    float e = __builtin_amdgcn_exp2f(acc[rt][r]);
                    pp[rt][r] += e;
                    ce += e;
                }
            // reduce col-partial across the 4 g-groups (lanes cl+16g share a col)
            ce += __shfl_xor(ce, 16);
            ce += __shfl_xor(ce, 32);
            if (lane < 16) ldsC[cur][w][ct * 16 + lane] = ce;   // wave's 64-row col-sum
        }
        __syncthreads();   // publishes ldsC[cur] + drains staging/reads

        if (offdiag && tid < 64) {   // cross-wave col reduce, one writer per col
            float cs = ldsC[cur][0][tid] + ldsC[cur][1][tid] +
                       ldsC[cur][2][tid] + ldsC[cur][3][tid];
            partial[(size_t)a * N2 + colbase + s * 64 + tid] = cs;
        }
        // ldsC[cur] next written in step s+2, after sync of s+1 -> race-free ping-pong
    }

    // row-partials: reduce across the 16 col-lanes (cl) within each g-group
    #pragma unroll
    for (int rt = 0; rt < 4; ++rt) {
        #pragma unroll
        for (int r = 0; r < 4; ++r) {
            float v = pp[rt][r];
            v += __shfl_xor(v, 1);
            v += __shfl_xor(v, 2);
            v += __shfl_xor(v, 4);
            v += __shfl_xor(v, 8);
            if (cl == 0)
                partial[(size_t)b * N2 + rowbase + w * 64 + rt * 16 + g * 4 + r] = v;
        }
    }
}

// ---- K3: per-row loss over 32 blocks; last block finishes the mean ----
__global__ __launch_bounds__(256) void k_loss(const float* __restrict__ partial,
                                              const float* __restrict__ diag,
                                              const float* __restrict__ posv,
                                              float* __restrict__ blocksum,
                                              unsigned int* __restrict__ counter,
                                              float* __restrict__ out) {
    int row = blockIdx.x * 256 + threadIdx.x;
    float sum = 0.0f;
    #pragma unroll
    for (int c = 0; c < 32; ++c) sum += partial[(size_t)c * N2 + row];
    sum -= __builtin_amdgcn_exp2f(diag[row]);           // remove diagonal term
    float lr = __builtin_amdgcn_logf(sum) * LN2 - posv[row & (BROWS - 1)];
    lr = wave_reduce(lr);
    __shared__ float red[4];
    if ((threadIdx.x & 63) == 0) red[threadIdx.x >> 6] = lr;
    __syncthreads();
    if (threadIdx.x == 0) {
        blocksum[blockIdx.x] = red[0] + red[1] + red[2] + red[3];
        __threadfence();                                  // publish blocksum
        unsigned int old = atomicAdd(counter, 1u);        // device-scope
        if (old == 31u) {                                 // last block finishes
            __threadfence();                              // acquire
            volatile const float* bs = blocksum;
            float t = 0.0f;
            for (int i = 0; i < 32; ++i) t += bs[i];
            out[0] = t * (1.0f / N2);
        }
    }
}

extern "C" void kernel_launch(void* const* d_in, const int* in_sizes, int n_in,
                              void* d_out, int out_size, void* d_ws, size_t ws_size,
                              hipStream_t stream) {
    const float* zi = (const float*)d_in[0];
    const float* zj = (const float*)d_in[1];
    float* out = (float*)d_out;

    char* ws = (char*)d_ws;
    unsigned short* zn    = (unsigned short*)ws;                       // 4 MB
    float* diag           = (float*)(ws + (4u << 20));                 // 32 KB
    float* posv           = (float*)(ws + (4u << 20) + (32u << 10));   // 16 KB
    float* blocksum       = (float*)(ws + (4u << 20) + (48u << 10));   // 128 B
    unsigned int* counter = (unsigned int*)(ws + (4u << 20) + (52u << 10));
    float* partial        = (float*)(ws + (4u << 20) + (64u << 10));   // 1 MB (32 slots)

    k_norm_pos<<<BROWS / 4, 256, 0, stream>>>(zi, zj, zn, diag, posv, counter);
    k_simsum<<<528, 256, 0, stream>>>(zn, partial);
    k_loss<<<32, 256, 0, stream>>>(partial, diag, posv, blocksum, counter, out);
}